// Round 1
// baseline (2228.280 us; speedup 1.0000x reference)
//
#include <hip/hip_runtime.h>
#include <hip/hip_bf16.h>

typedef __bf16 bf16_t;
typedef bf16_t bf16x8_t __attribute__((ext_vector_type(8)));
typedef bf16_t bf16x4_t __attribute__((ext_vector_type(4)));
typedef float f32x4_t __attribute__((ext_vector_type(4)));

#define NROWS 8192
#define DDIM  4096

#define BM 128
#define BN 128
#define BK 32
#define LSTR 40  // LDS row stride (bf16 elems): 32 + 8 pad = 80B, keeps 16B alignment, breaks bank conflicts

// Stage a 128x32 fp32 tile (row-major, leading dim ld) into hi/lo bf16 LDS tiles.
// 256 threads; each thread moves 4 float4 (16 elems).
__device__ __forceinline__ void stage_split(const float* __restrict__ src, long ld,
                                            bf16_t (&hi)[BM][LSTR],
                                            bf16_t (&lo)[BM][LSTR],
                                            int t) {
#pragma unroll
  for (int i = 0; i < 4; ++i) {
    const int f   = i * 256 + t;     // float4 index within tile, 0..1023
    const int row = f >> 3;          // 8 float4 per 32-wide row
    const int kq  = (f & 7) << 2;    // k offset (multiple of 4)
    const float4 v = *reinterpret_cast<const float4*>(src + (long)row * ld + kq);
    float vv[4] = {v.x, v.y, v.z, v.w};
    bf16x4_t h, l;
#pragma unroll
    for (int c = 0; c < 4; ++c) {
      bf16_t hh = (bf16_t)vv[c];
      h[c] = hh;
      l[c] = (bf16_t)(vv[c] - (float)hh);
    }
    *reinterpret_cast<bf16x4_t*>(&hi[row][kq]) = h;
    *reinterpret_cast<bf16x4_t*>(&lo[row][kq]) = l;
  }
}

// NT GEMM core: acc += A[128 rows] . B[128 rows]^T over K, split-bf16 3-pass MFMA.
// Abase/Bbase point at the first row of each block's tile (row-major, leading dim K).
__device__ __forceinline__ void gemm_core(const float* __restrict__ Abase,
                                          const float* __restrict__ Bbase,
                                          int K,
                                          bf16_t (&Ahi)[BM][LSTR], bf16_t (&Alo)[BM][LSTR],
                                          bf16_t (&Bhi)[BM][LSTR], bf16_t (&Blo)[BM][LSTR],
                                          f32x4_t (&acc)[4][4]) {
  const int t    = threadIdx.x;
  const int lane = t & 63;
  const int wr   = ((t >> 6) >> 1) * 64;  // wave row offset (2x2 wave grid, 64x64 per wave)
  const int wc   = ((t >> 6) & 1) * 64;
  const int fr   = lane & 15;             // fragment row
  const int kg   = lane >> 4;             // k-group 0..3 (8 bf16 each)

#pragma unroll
  for (int m = 0; m < 4; ++m)
#pragma unroll
    for (int n = 0; n < 4; ++n) acc[m][n] = f32x4_t{0.f, 0.f, 0.f, 0.f};

  for (int k0 = 0; k0 < K; k0 += BK) {
    __syncthreads();  // protect previous iteration's LDS reads
    stage_split(Abase + k0, K, Ahi, Alo, t);
    stage_split(Bbase + k0, K, Bhi, Blo, t);
    __syncthreads();

    bf16x8_t ah[4], al[4], bh[4], bl[4];
#pragma unroll
    for (int m = 0; m < 4; ++m) {
      ah[m] = *reinterpret_cast<const bf16x8_t*>(&Ahi[wr + m * 16 + fr][kg * 8]);
      al[m] = *reinterpret_cast<const bf16x8_t*>(&Alo[wr + m * 16 + fr][kg * 8]);
    }
#pragma unroll
    for (int n = 0; n < 4; ++n) {
      bh[n] = *reinterpret_cast<const bf16x8_t*>(&Bhi[wc + n * 16 + fr][kg * 8]);
      bl[n] = *reinterpret_cast<const bf16x8_t*>(&Blo[wc + n * 16 + fr][kg * 8]);
    }

#pragma unroll
    for (int m = 0; m < 4; ++m)
#pragma unroll
      for (int n = 0; n < 4; ++n) {
        acc[m][n] = __builtin_amdgcn_mfma_f32_16x16x32_bf16(ah[m], bh[n], acc[m][n], 0, 0, 0);
        acc[m][n] = __builtin_amdgcn_mfma_f32_16x16x32_bf16(ah[m], bl[n], acc[m][n], 0, 0, 0);
        acc[m][n] = __builtin_amdgcn_mfma_f32_16x16x32_bf16(al[m], bh[n], acc[m][n], 0, 0, 0);
      }
  }
}

// GEMM1: xp = relu(x @ W^T + b).  x:[8192,4096] W:[4096,4096] (both row-major, contract inner dim)
__global__ __launch_bounds__(256) void k_gemm1(const float* __restrict__ x,
                                               const float* __restrict__ W,
                                               const float* __restrict__ bias,
                                               float* __restrict__ xp) {
  __shared__ alignas(16) bf16_t Ahi[BM][LSTR];
  __shared__ alignas(16) bf16_t Alo[BM][LSTR];
  __shared__ alignas(16) bf16_t Bhi[BM][LSTR];
  __shared__ alignas(16) bf16_t Blo[BM][LSTR];

  const long brow = (long)blockIdx.y * BM;
  const long bcol = (long)blockIdx.x * BN;

  f32x4_t acc[4][4];
  gemm_core(x + brow * DDIM, W + bcol * DDIM, DDIM, Ahi, Alo, Bhi, Blo, acc);

  const int t = threadIdx.x, lane = t & 63;
  const int wr = ((t >> 6) >> 1) * 64, wc = ((t >> 6) & 1) * 64;
  const int cr = (lane >> 4) * 4, cc = lane & 15;

#pragma unroll
  for (int n = 0; n < 4; ++n) {
    const long col = bcol + wc + n * 16 + cc;
    const float bb = bias[col];
#pragma unroll
    for (int m = 0; m < 4; ++m) {
      const long row0 = brow + wr + m * 16 + cr;
#pragma unroll
      for (int r = 0; r < 4; ++r) {
        float v = acc[m][n][r] + bb;
        xp[(row0 + r) * (long)DDIM + col] = fmaxf(v, 0.f);
      }
    }
  }
}

// GEMM2: scores[i][j] = xp_i . xp_j + rw*(i-j), lower-triangular blocks only.
__global__ __launch_bounds__(256) void k_gemm2(const float* __restrict__ xp,
                                               const float* __restrict__ rwp,
                                               float* __restrict__ out) {
  const int bx = blockIdx.x, by = blockIdx.y;
  if (bx > by) return;  // strictly upper blocks produce nothing (softmax writes zeros there)

  __shared__ alignas(16) bf16_t Ahi[BM][LSTR];
  __shared__ alignas(16) bf16_t Alo[BM][LSTR];
  __shared__ alignas(16) bf16_t Bhi[BM][LSTR];
  __shared__ alignas(16) bf16_t Blo[BM][LSTR];

  const long brow = (long)by * BM;
  const long bcol = (long)bx * BN;

  f32x4_t acc[4][4];
  gemm_core(xp + brow * DDIM, xp + bcol * DDIM, DDIM, Ahi, Alo, Bhi, Blo, acc);

  const float rw = rwp[0];
  const int t = threadIdx.x, lane = t & 63;
  const int wr = ((t >> 6) >> 1) * 64, wc = ((t >> 6) & 1) * 64;
  const int cr = (lane >> 4) * 4, cc = lane & 15;

#pragma unroll
  for (int n = 0; n < 4; ++n) {
    const long gj = bcol + wc + n * 16 + cc;
#pragma unroll
    for (int m = 0; m < 4; ++m) {
      const long gi0 = brow + wr + m * 16 + cr;
#pragma unroll
      for (int r = 0; r < 4; ++r) {
        const long gi = gi0 + r;
        // recency bias: only j<i entries are ever read by softmax; others are dont-care
        out[gi * (long)NROWS + gj] = acc[m][n][r] + rw * (float)(gi - gj);
      }
    }
  }
}

// Row softmax over j < i, writes zeros for j >= i. Row 0 -> all zeros. In-place on out.
__global__ __launch_bounds__(256) void k_row_softmax(float* __restrict__ out, int n) {
  const int i = blockIdx.x;
  float* row = out + (size_t)i * n;
  const int L = i;  // valid prefix length
  const int t = threadIdx.x;
  __shared__ float red[4];

  float m = -3.402823466e+38f;
  for (int j = t; j < L; j += 256) m = fmaxf(m, row[j]);
#pragma unroll
  for (int o = 32; o > 0; o >>= 1) m = fmaxf(m, __shfl_down(m, o, 64));
  if ((t & 63) == 0) red[t >> 6] = m;
  __syncthreads();
  m = fmaxf(fmaxf(red[0], red[1]), fmaxf(red[2], red[3]));
  __syncthreads();  // before reusing red

  float s = 0.f;
  for (int j = t; j < L; j += 256) s += expf(row[j] - m);
#pragma unroll
  for (int o = 32; o > 0; o >>= 1) s += __shfl_down(s, o, 64);
  if ((t & 63) == 0) red[t >> 6] = s;
  __syncthreads();
  s = red[0] + red[1] + red[2] + red[3];
  const float inv = (L > 0) ? 1.f / s : 0.f;

  for (int j = t; j < n; j += 256) {
    row[j] = (j < L) ? expf(row[j] - m) * inv : 0.f;
  }
}

extern "C" void kernel_launch(void* const* d_in, const int* in_sizes, int n_in,
                              void* d_out, int out_size, void* d_ws, size_t ws_size,
                              hipStream_t stream) {
  (void)in_sizes; (void)n_in; (void)out_size; (void)ws_size;
  const float* x  = (const float*)d_in[0];
  const float* W  = (const float*)d_in[1];
  const float* b  = (const float*)d_in[2];
  const float* rw = (const float*)d_in[3];
  float* out = (float*)d_out;
  float* xp  = (float*)d_ws;  // 8192*4096 fp32 = 128 MB scratch

  k_gemm1<<<dim3(DDIM / BN, NROWS / BM), 256, 0, stream>>>(x, W, b, xp);
  k_gemm2<<<dim3(NROWS / BN, NROWS / BM), 256, 0, stream>>>(xp, rw, out);
  k_row_softmax<<<NROWS, 256, 0, stream>>>(out, NROWS);
}

// Round 2
// 1989.117 us; speedup vs baseline: 1.1202x; 1.1202x over previous
//
#include <hip/hip_runtime.h>
#include <hip/hip_bf16.h>
#include <stdint.h>

typedef __bf16 bf16_t;
typedef bf16_t bf16x8_t __attribute__((ext_vector_type(8)));
typedef bf16_t bf16x4_t __attribute__((ext_vector_type(4)));
typedef float f32x4_t __attribute__((ext_vector_type(4)));

#define NROWS 8192
#define DDIM  4096
#define BK 32
#define LSTR 40  // slow-path LDS stride

// ---------------- async 16B global->LDS ----------------
__device__ __forceinline__ void gload16(const void* g, void* s) {
  __builtin_amdgcn_global_load_lds(
      (const __attribute__((address_space(1))) void*)g,
      (__attribute__((address_space(3))) void*)s, 16, 0, 0);
}

// ---------------- presplit: fp32 -> (hi,lo) bf16 ----------------
__global__ __launch_bounds__(256) void k_split(const float* __restrict__ in,
                                               bf16_t* __restrict__ hi,
                                               bf16_t* __restrict__ lo) {
  const long i = ((long)blockIdx.x * 256 + threadIdx.x) * 4;
  const float4 v = *reinterpret_cast<const float4*>(in + i);
  float vv[4] = {v.x, v.y, v.z, v.w};
  bf16x4_t h, l;
#pragma unroll
  for (int c = 0; c < 4; ++c) {
    bf16_t hh = (bf16_t)vv[c];
    h[c] = hh;
    l[c] = (bf16_t)(vv[c] - (float)hh);
  }
  *reinterpret_cast<bf16x4_t*>(hi + i) = h;
  *reinterpret_cast<bf16x4_t*>(lo + i) = l;
}

// ---------------- fast NT GEMM core (m97-style) ----------------
// acc += A(128 rows) . B(128 rows)^T over K, split-bf16 3-pass MFMA.
// A/B given as (hi,lo) bf16 row-major panels already offset to the block's first row.
__device__ __forceinline__ void gemm_fast_core(
    const bf16_t* __restrict__ Ah, const bf16_t* __restrict__ Al, long lda,
    const bf16_t* __restrict__ Bh, const bf16_t* __restrict__ Bl, long ldb,
    int K, bf16_t (&sm)[4][128][BK], f32x4_t (&acc)[4][4]) {
  const int t = threadIdx.x;
  const int lane = t & 63;
  const int w = t >> 6;
  const int wr = (w >> 1) * 64, wc = (w & 1) * 64;
  const int fr = lane & 15, kg = lane >> 4;

  // staging geometry: per (tile, half-of-128-rows), wave w covers rows [h*64+w*16, +16)
  // LDS dest is wave-uniform base + lane*16 (hardware); rows are 64B so 4 lanes/row.
  const int srow = w * 16 + (lane >> 2);   // 0..63 within a half
  const int scol = (lane & 3) * 8;         // bf16 elems

  const bf16_t* gsrc[8];
  gsrc[0] = Ah + (long)srow * lda + scol;
  gsrc[1] = Ah + (long)(srow + 64) * lda + scol;
  gsrc[2] = Al + (long)srow * lda + scol;
  gsrc[3] = Al + (long)(srow + 64) * lda + scol;
  gsrc[4] = Bh + (long)srow * ldb + scol;
  gsrc[5] = Bh + (long)(srow + 64) * ldb + scol;
  gsrc[6] = Bl + (long)srow * ldb + scol;
  gsrc[7] = Bl + (long)(srow + 64) * ldb + scol;

  bf16_t* ldst[8];
  ldst[0] = &sm[0][w * 16][0];
  ldst[1] = &sm[0][64 + w * 16][0];
  ldst[2] = &sm[1][w * 16][0];
  ldst[3] = &sm[1][64 + w * 16][0];
  ldst[4] = &sm[2][w * 16][0];
  ldst[5] = &sm[2][64 + w * 16][0];
  ldst[6] = &sm[3][w * 16][0];
  ldst[7] = &sm[3][64 + w * 16][0];

#pragma unroll
  for (int m = 0; m < 4; ++m)
#pragma unroll
    for (int n = 0; n < 4; ++n) acc[m][n] = f32x4_t{0.f, 0.f, 0.f, 0.f};

  for (int k0 = 0; k0 < K; k0 += BK) {
    __syncthreads();  // previous iteration's ds_reads done before overwrite
#pragma unroll
    for (int q = 0; q < 8; ++q) gload16(gsrc[q] + k0, ldst[q]);
    __syncthreads();  // compiler drains vmcnt(0) before the barrier -> stage complete

    bf16x8_t ah[4], al[4], bh[4], bl[4];
#pragma unroll
    for (int m = 0; m < 4; ++m) {
      ah[m] = *reinterpret_cast<const bf16x8_t*>(&sm[0][wr + m * 16 + fr][kg * 8]);
      al[m] = *reinterpret_cast<const bf16x8_t*>(&sm[1][wr + m * 16 + fr][kg * 8]);
      bh[m] = *reinterpret_cast<const bf16x8_t*>(&sm[2][wc + m * 16 + fr][kg * 8]);
      bl[m] = *reinterpret_cast<const bf16x8_t*>(&sm[3][wc + m * 16 + fr][kg * 8]);
    }
#pragma unroll
    for (int m = 0; m < 4; ++m)
#pragma unroll
      for (int n = 0; n < 4; ++n) {
        acc[m][n] = __builtin_amdgcn_mfma_f32_16x16x32_bf16(ah[m], bh[n], acc[m][n], 0, 0, 0);
        acc[m][n] = __builtin_amdgcn_mfma_f32_16x16x32_bf16(ah[m], bl[n], acc[m][n], 0, 0, 0);
        acc[m][n] = __builtin_amdgcn_mfma_f32_16x16x32_bf16(al[m], bh[n], acc[m][n], 0, 0, 0);
      }
  }
}

// ---------------- GEMM1 fast: xp(hi,lo) = split(relu(x @ W^T + b)) ----------------
__global__ __launch_bounds__(256) void k_gemm1_fast(
    const bf16_t* __restrict__ xh, const bf16_t* __restrict__ xl,
    const bf16_t* __restrict__ Wh, const bf16_t* __restrict__ Wl,
    const float* __restrict__ bias,
    bf16_t* __restrict__ xph, bf16_t* __restrict__ xpl) {
  __shared__ alignas(16) bf16_t sm[4][128][BK];
  const long brow = (long)blockIdx.y * 128;
  const long bcol = (long)blockIdx.x * 128;

  f32x4_t acc[4][4];
  gemm_fast_core(xh + brow * DDIM, xl + brow * DDIM, DDIM,
                 Wh + bcol * DDIM, Wl + bcol * DDIM, DDIM, DDIM, sm, acc);

  const int t = threadIdx.x, lane = t & 63, w = t >> 6;
  const int wr = (w >> 1) * 64, wc = (w & 1) * 64;
  const int cr = (lane >> 4) * 4, cc = lane & 15;
#pragma unroll
  for (int n = 0; n < 4; ++n) {
    const long col = bcol + wc + n * 16 + cc;
    const float bb = bias[col];
#pragma unroll
    for (int m = 0; m < 4; ++m) {
      const long row0 = brow + wr + m * 16 + cr;
#pragma unroll
      for (int r = 0; r < 4; ++r) {
        const float v = fmaxf(acc[m][n][r] + bb, 0.f);
        const bf16_t h = (bf16_t)v;
        xph[(row0 + r) * (long)DDIM + col] = h;
        xpl[(row0 + r) * (long)DDIM + col] = (bf16_t)(v - (float)h);
      }
    }
  }
}

// ---------------- GEMM2 fast: lower-tri blocks only (1D triangular grid) ----------------
__global__ __launch_bounds__(256) void k_gemm2_fast(
    const bf16_t* __restrict__ xph, const bf16_t* __restrict__ xpl,
    const float* __restrict__ rwp, float* __restrict__ out) {
  const int bid = blockIdx.x;
  int by = (int)((sqrtf(8.f * (float)bid + 1.f) - 1.f) * 0.5f);
  while ((by + 1) * (by + 2) / 2 <= bid) ++by;
  while (by * (by + 1) / 2 > bid) --by;
  const int bx = bid - by * (by + 1) / 2;

  __shared__ alignas(16) bf16_t sm[4][128][BK];
  const long brow = (long)by * 128;
  const long bcol = (long)bx * 128;

  f32x4_t acc[4][4];
  gemm_fast_core(xph + brow * DDIM, xpl + brow * DDIM, DDIM,
                 xph + bcol * DDIM, xpl + bcol * DDIM, DDIM, DDIM, sm, acc);

  const float rw = rwp[0];
  const int t = threadIdx.x, lane = t & 63, w = t >> 6;
  const int wr = (w >> 1) * 64, wc = (w & 1) * 64;
  const int cr = (lane >> 4) * 4, cc = lane & 15;
#pragma unroll
  for (int n = 0; n < 4; ++n) {
    const long gj = bcol + wc + n * 16 + cc;
#pragma unroll
    for (int m = 0; m < 4; ++m) {
      const long gi0 = brow + wr + m * 16 + cr;
#pragma unroll
      for (int r = 0; r < 4; ++r) {
        const long gi = gi0 + r;
        out[gi * (long)NROWS + gj] = acc[m][n][r] + rw * (float)(gi - gj);
      }
    }
  }
}

// ---------------- slow-path GEMM1 (fp32 in-LDS split; proven) ----------------
__device__ __forceinline__ void stage_split(const float* __restrict__ src, long ld,
                                            bf16_t (&hi)[128][LSTR],
                                            bf16_t (&lo)[128][LSTR],
                                            int t) {
#pragma unroll
  for (int i = 0; i < 4; ++i) {
    const int f = i * 256 + t;
    const int row = f >> 3;
    const int kq = (f & 7) << 2;
    const float4 v = *reinterpret_cast<const float4*>(src + (long)row * ld + kq);
    float vv[4] = {v.x, v.y, v.z, v.w};
    bf16x4_t h, l;
#pragma unroll
    for (int c = 0; c < 4; ++c) {
      bf16_t hh = (bf16_t)vv[c];
      h[c] = hh;
      l[c] = (bf16_t)(vv[c] - (float)hh);
    }
    *reinterpret_cast<bf16x4_t*>(&hi[row][kq]) = h;
    *reinterpret_cast<bf16x4_t*>(&lo[row][kq]) = l;
  }
}

__global__ __launch_bounds__(256) void k_gemm1_slow(
    const float* __restrict__ x, const float* __restrict__ W,
    const float* __restrict__ bias,
    bf16_t* __restrict__ xph, bf16_t* __restrict__ xpl) {
  __shared__ alignas(16) bf16_t Ahi[128][LSTR];
  __shared__ alignas(16) bf16_t Alo[128][LSTR];
  __shared__ alignas(16) bf16_t Bhi[128][LSTR];
  __shared__ alignas(16) bf16_t Blo[128][LSTR];

  const long brow = (long)blockIdx.y * 128;
  const long bcol = (long)blockIdx.x * 128;
  const int t = threadIdx.x, lane = t & 63;
  const int wr = ((t >> 6) >> 1) * 64, wc = ((t >> 6) & 1) * 64;
  const int fr = lane & 15, kg = lane >> 4;

  f32x4_t acc[4][4];
#pragma unroll
  for (int m = 0; m < 4; ++m)
#pragma unroll
    for (int n = 0; n < 4; ++n) acc[m][n] = f32x4_t{0.f, 0.f, 0.f, 0.f};

  const float* Abase = x + brow * DDIM;
  const float* Bbase = W + bcol * DDIM;
  for (int k0 = 0; k0 < DDIM; k0 += BK) {
    __syncthreads();
    stage_split(Abase + k0, DDIM, Ahi, Alo, t);
    stage_split(Bbase + k0, DDIM, Bhi, Blo, t);
    __syncthreads();

    bf16x8_t ah[4], al[4], bh[4], bl[4];
#pragma unroll
    for (int m = 0; m < 4; ++m) {
      ah[m] = *reinterpret_cast<const bf16x8_t*>(&Ahi[wr + m * 16 + fr][kg * 8]);
      al[m] = *reinterpret_cast<const bf16x8_t*>(&Alo[wr + m * 16 + fr][kg * 8]);
      bh[m] = *reinterpret_cast<const bf16x8_t*>(&Bhi[wc + m * 16 + fr][kg * 8]);
      bl[m] = *reinterpret_cast<const bf16x8_t*>(&Blo[wc + m * 16 + fr][kg * 8]);
    }
#pragma unroll
    for (int m = 0; m < 4; ++m)
#pragma unroll
      for (int n = 0; n < 4; ++n) {
        acc[m][n] = __builtin_amdgcn_mfma_f32_16x16x32_bf16(ah[m], bh[n], acc[m][n], 0, 0, 0);
        acc[m][n] = __builtin_amdgcn_mfma_f32_16x16x32_bf16(ah[m], bl[n], acc[m][n], 0, 0, 0);
        acc[m][n] = __builtin_amdgcn_mfma_f32_16x16x32_bf16(al[m], bh[n], acc[m][n], 0, 0, 0);
      }
  }

  const int cr = (lane >> 4) * 4, cc = lane & 15;
#pragma unroll
  for (int n = 0; n < 4; ++n) {
    const long col = bcol + wc + n * 16 + cc;
    const float bb = bias[col];
#pragma unroll
    for (int m = 0; m < 4; ++m) {
      const long row0 = brow + wr + m * 16 + cr;
#pragma unroll
      for (int r = 0; r < 4; ++r) {
        const float v = fmaxf(acc[m][n][r] + bb, 0.f);
        const bf16_t h = (bf16_t)v;
        xph[(row0 + r) * (long)DDIM + col] = h;
        xpl[(row0 + r) * (long)DDIM + col] = (bf16_t)(v - (float)h);
      }
    }
  }
}

// ---------------- row softmax over j<i; zeros elsewhere; row 0 all zeros ----------------
__global__ __launch_bounds__(256) void k_row_softmax(float* __restrict__ out, int n) {
  const int i = blockIdx.x;
  float* row = out + (size_t)i * n;
  const int L = i;
  const int t = threadIdx.x;
  __shared__ float red[4];

  float m = -3.402823466e+38f;
  for (int j = t; j < L; j += 256) m = fmaxf(m, row[j]);
#pragma unroll
  for (int o = 32; o > 0; o >>= 1) m = fmaxf(m, __shfl_down(m, o, 64));
  if ((t & 63) == 0) red[t >> 6] = m;
  __syncthreads();
  m = fmaxf(fmaxf(red[0], red[1]), fmaxf(red[2], red[3]));
  __syncthreads();

  float s = 0.f;
  for (int j = t; j < L; j += 256) s += expf(row[j] - m);
#pragma unroll
  for (int o = 32; o > 0; o >>= 1) s += __shfl_down(s, o, 64);
  if ((t & 63) == 0) red[t >> 6] = s;
  __syncthreads();
  s = red[0] + red[1] + red[2] + red[3];
  const float inv = (L > 0) ? 1.f / s : 0.f;

  for (int j = t; j < n; j += 256) {
    row[j] = (j < L) ? expf(row[j] - m) * inv : 0.f;
  }
}

extern "C" void kernel_launch(void* const* d_in, const int* in_sizes, int n_in,
                              void* d_out, int out_size, void* d_ws, size_t ws_size,
                              hipStream_t stream) {
  (void)in_sizes; (void)n_in; (void)out_size;
  const float* x = (const float*)d_in[0];
  const float* W = (const float*)d_in[1];
  const float* b = (const float*)d_in[2];
  const float* rw = (const float*)d_in[3];
  float* out = (float*)d_out;

  const size_t NX = (size_t)NROWS * DDIM;  // 33.55M
  const size_t NW = (size_t)DDIM * DDIM;   // 16.78M
  char* ws = (char*)d_ws;
  bf16_t* xph = (bf16_t*)ws;                       // 64MB
  bf16_t* xpl = (bf16_t*)(ws + (NX * 2));          // +64MB

  const size_t need_full = NX * 2 * 2 /*xph,xpl*/ + NX * 2 * 2 /*xh,xl*/ + NW * 2 * 2 /*Wh,Wl*/;
  if (ws_size >= need_full) {
    bf16_t* xh = (bf16_t*)(ws + NX * 4);
    bf16_t* xl = (bf16_t*)(ws + NX * 4 + NX * 2);
    bf16_t* Wh = (bf16_t*)(ws + NX * 8);
    bf16_t* Wl = (bf16_t*)(ws + NX * 8 + NW * 2);
    k_split<<<(int)(NX / 1024), 256, 0, stream>>>(x, xh, xl);
    k_split<<<(int)(NW / 1024), 256, 0, stream>>>(W, Wh, Wl);
    k_gemm1_fast<<<dim3(DDIM / 128, NROWS / 128), 256, 0, stream>>>(xh, xl, Wh, Wl, b, xph, xpl);
  } else {
    k_gemm1_slow<<<dim3(DDIM / 128, NROWS / 128), 256, 0, stream>>>(x, W, b, xph, xpl);
  }

  const int ntri = (NROWS / 128) * (NROWS / 128 + 1) / 2;  // 2080
  k_gemm2_fast<<<ntri, 256, 0, stream>>>(xph, xpl, rw, out);
  k_row_softmax<<<NROWS, 256, 0, stream>>>(out, NROWS);
}

// Round 3
// 1697.800 us; speedup vs baseline: 1.3125x; 1.1716x over previous
//
#include <hip/hip_runtime.h>
#include <hip/hip_bf16.h>
#include <stdint.h>

typedef __bf16 bf16_t;
typedef bf16_t bf16x8_t __attribute__((ext_vector_type(8)));
typedef bf16_t bf16x4_t __attribute__((ext_vector_type(4)));
typedef float f32x4_t __attribute__((ext_vector_type(4)));

#define NROWS 8192
#define DDIM  4096
#define BK 32
#define KTILES (DDIM / BK)  // 128
#define LSTR 40             // slow-path LDS stride

// ---------------- async 16B global->LDS ----------------
__device__ __forceinline__ void gload16(const void* g, void* s) {
  __builtin_amdgcn_global_load_lds(
      (const __attribute__((address_space(1))) void*)g,
      (__attribute__((address_space(3))) void*)s, 16, 0, 0);
}

// ---------------- presplit: fp32 -> (hi,lo) bf16 ----------------
__global__ __launch_bounds__(256) void k_split(const float* __restrict__ in,
                                               bf16_t* __restrict__ hi,
                                               bf16_t* __restrict__ lo) {
  const long i = ((long)blockIdx.x * 256 + threadIdx.x) * 4;
  const float4 v = *reinterpret_cast<const float4*>(in + i);
  float vv[4] = {v.x, v.y, v.z, v.w};
  bf16x4_t h, l;
#pragma unroll
  for (int c = 0; c < 4; ++c) {
    bf16_t hh = (bf16_t)vv[c];
    h[c] = hh;
    l[c] = (bf16_t)(vv[c] - (float)hh);
  }
  *reinterpret_cast<bf16x4_t*>(hi + i) = h;
  *reinterpret_cast<bf16x4_t*>(lo + i) = l;
}

// ---------------- 256x256 3-phase pipelined split-bf16 NT GEMM core ----------------
// planes: 0=Ah 1=Al 2=Bh 3=Bl. LDS: [2 buf][4 planes][256 rows][32 cols] bf16 = 128 KiB.
typedef bf16_t lds_buf_t[4][256][BK];

__device__ __forceinline__ void gemm_core256(
    const bf16_t* __restrict__ pAh, const bf16_t* __restrict__ pAl, long lda,
    const bf16_t* __restrict__ pBh, const bf16_t* __restrict__ pBl, long ldb,
    lds_buf_t* sm, f32x4_t (&acc)[8][4]) {
  const int t = threadIdx.x, lane = t & 63, w = t >> 6;
  const int fr = lane & 15, kg = lane >> 4;
  const int wr = (w >> 2) * 128, wc = (w & 3) * 64;
  const int w32 = w * 32;
  const int sr0 = w32 + (lane >> 2);   // staging row for this lane (issue 0)
  const int sg = (lane & 3) * 8;       // staging col (bf16 elems, 16B granule)

#pragma unroll
  for (int m = 0; m < 8; ++m)
#pragma unroll
    for (int n = 0; n < 4; ++n) acc[m][n] = f32x4_t{0.f, 0.f, 0.f, 0.f};

  const bf16_t* gAh = pAh + (long)sr0 * lda + sg;
  const bf16_t* gAl = pAl + (long)sr0 * lda + sg;
  const bf16_t* gBh = pBh + (long)sr0 * ldb + sg;
  const bf16_t* gBl = pBl + (long)sr0 * ldb + sg;
  const long a16 = 16 * lda, b16 = 16 * ldb;

  // dest is wave-uniform base; HW adds lane*16 -> row w32+(lane>>2)[+16], granule lane&3
  auto issue = [&](int buf, int plane, const bf16_t* g, long ld16, int k0) {
    gload16(g + k0, &sm[buf][plane][w32][0]);
    gload16(g + ld16 + k0, &sm[buf][plane][w32 + 16][0]);
  };

  bf16x8_t ah[8], al[8], bh[4], bl[4];
  auto read8 = [&](bf16x8_t(&R)[8], int buf, int plane) {
#pragma unroll
    for (int m = 0; m < 8; ++m)
      R[m] = *reinterpret_cast<const bf16x8_t*>(&sm[buf][plane][wr + m * 16 + fr][kg * 8]);
  };
  auto read4 = [&](bf16x8_t(&R)[4], int buf, int plane) {
#pragma unroll
    for (int n = 0; n < 4; ++n)
      R[n] = *reinterpret_cast<const bf16x8_t*>(&sm[buf][plane][wc + n * 16 + fr][kg * 8]);
  };
  auto mfma32 = [&](bf16x8_t(&A)[8], bf16x8_t(&B)[4]) {
    __builtin_amdgcn_s_setprio(1);
#pragma unroll
    for (int m = 0; m < 8; ++m)
#pragma unroll
      for (int n = 0; n < 4; ++n)
        acc[m][n] = __builtin_amdgcn_mfma_f32_16x16x32_bf16(A[m], B[n], acc[m][n], 0, 0, 0);
    __builtin_amdgcn_s_setprio(0);
  };

  // prologue: tile 0, issue order Ah,Bh,Bl,Al (8 loads/thread)
  issue(0, 0, gAh, a16, 0);
  issue(0, 2, gBh, b16, 0);
  issue(0, 3, gBl, b16, 0);
  issue(0, 1, gAl, a16, 0);
  asm volatile("s_waitcnt vmcnt(4)" ::: "memory");  // Ah,Bh(0) landed
  __builtin_amdgcn_s_barrier();

  // steady state: per-thread outstanding entering phase0 = [Bl(kt),Al(kt)] (4)
  for (int kt = 0; kt < KTILES - 1; ++kt) {
    const int c = kt & 1;
    const int k0 = (kt + 1) * BK;
    // ---- phase 0: Ah*Bh ----
    read8(ah, c, 0);
    read4(bh, c, 2);
    issue(c ^ 1, 0, gAh, a16, k0);
    issue(c ^ 1, 2, gBh, b16, k0);
    __builtin_amdgcn_s_barrier();
    mfma32(ah, bh);
    asm volatile("s_waitcnt vmcnt(6)" ::: "memory");  // Bl(kt) landed
    __builtin_amdgcn_s_barrier();
    // ---- phase 1: Ah*Bl ----
    read4(bl, c, 3);
    issue(c ^ 1, 3, gBl, b16, k0);
    __builtin_amdgcn_s_barrier();
    mfma32(ah, bl);
    asm volatile("s_waitcnt vmcnt(6)" ::: "memory");  // Al(kt) landed
    __builtin_amdgcn_s_barrier();
    // ---- phase 2: Al*Bh ----
    read8(al, c, 1);
    issue(c ^ 1, 1, gAl, a16, k0);
    __builtin_amdgcn_s_barrier();
    mfma32(al, bh);
    asm volatile("s_waitcnt vmcnt(4)" ::: "memory");  // Ah,Bh(kt+1) landed
    __builtin_amdgcn_s_barrier();
  }
  // ---- peeled last tile: drain 2 -> 0 ----
  {
    const int c = (KTILES - 1) & 1;
    read8(ah, c, 0);
    read4(bh, c, 2);
    __builtin_amdgcn_s_barrier();
    mfma32(ah, bh);
    asm volatile("s_waitcnt vmcnt(2)" ::: "memory");  // Bl(last) landed
    __builtin_amdgcn_s_barrier();
    read4(bl, c, 3);
    __builtin_amdgcn_s_barrier();
    mfma32(ah, bl);
    asm volatile("s_waitcnt vmcnt(0)" ::: "memory");  // Al(last) landed
    __builtin_amdgcn_s_barrier();
    read8(al, c, 1);
    mfma32(al, bh);
  }
}

// ---------------- GEMM1 fast: xp(hi,lo) = split(relu(x @ W^T + b)) ----------------
__global__ __launch_bounds__(512, 2) void k_gemm1_256(
    const bf16_t* __restrict__ xh, const bf16_t* __restrict__ xl,
    const bf16_t* __restrict__ Wh, const bf16_t* __restrict__ Wl,
    const float* __restrict__ bias,
    bf16_t* __restrict__ xph, bf16_t* __restrict__ xpl) {
  extern __shared__ char smraw[];
  lds_buf_t* sm = (lds_buf_t*)smraw;

  int bid = (int)blockIdx.x;
  bid = (bid & 7) * 64 + (bid >> 3);  // 512 blocks, XCD-chunked (bijective)
  const int bx = bid & 15, by = bid >> 4;
  const long brow = (long)by * 256, bcol = (long)bx * 256;

  f32x4_t acc[8][4];
  gemm_core256(xh + brow * DDIM, xl + brow * DDIM, DDIM,
               Wh + bcol * DDIM, Wl + bcol * DDIM, DDIM, sm, acc);

  const int t = threadIdx.x, lane = t & 63, w = t >> 6;
  const int wr = (w >> 2) * 128, wc = (w & 3) * 64;
  const int cr = (lane >> 4) * 4, cc = lane & 15;
#pragma unroll
  for (int n = 0; n < 4; ++n) {
    const long col = bcol + wc + n * 16 + cc;
    const float bb = bias[col];
#pragma unroll
    for (int m = 0; m < 8; ++m) {
      const long row0 = brow + wr + m * 16 + cr;
#pragma unroll
      for (int r = 0; r < 4; ++r) {
        const float v = fmaxf(acc[m][n][r] + bb, 0.f);
        const bf16_t h = (bf16_t)v;
        xph[(row0 + r) * (long)DDIM + col] = h;
        xpl[(row0 + r) * (long)DDIM + col] = (bf16_t)(v - (float)h);
      }
    }
  }
}

// ---------------- GEMM2 fast: lower-tri 256x256 blocks ----------------
__global__ __launch_bounds__(512, 2) void k_gemm2_256(
    const bf16_t* __restrict__ xph, const bf16_t* __restrict__ xpl,
    const float* __restrict__ rwp, float* __restrict__ out) {
  extern __shared__ char smraw[];
  lds_buf_t* sm = (lds_buf_t*)smraw;

  int bid = (int)blockIdx.x;
  bid = (bid & 7) * 66 + (bid >> 3);  // 528 = 8*66, XCD-chunked (bijective)
  int by = (int)((sqrtf(8.f * (float)bid + 1.f) - 1.f) * 0.5f);
  while ((by + 1) * (by + 2) / 2 <= bid) ++by;
  while (by * (by + 1) / 2 > bid) --by;
  const int bx = bid - by * (by + 1) / 2;

  const long brow = (long)by * 256, bcol = (long)bx * 256;
  f32x4_t acc[8][4];
  gemm_core256(xph + brow * DDIM, xpl + brow * DDIM, DDIM,
               xph + bcol * DDIM, xpl + bcol * DDIM, DDIM, sm, acc);

  const float rw = rwp[0];
  const int t = threadIdx.x, lane = t & 63, w = t >> 6;
  const int wr = (w >> 2) * 128, wc = (w & 3) * 64;
  const int cr = (lane >> 4) * 4, cc = lane & 15;
#pragma unroll
  for (int n = 0; n < 4; ++n) {
    const long gj = bcol + wc + n * 16 + cc;
#pragma unroll
    for (int m = 0; m < 8; ++m) {
      const long gi0 = brow + wr + m * 16 + cr;
#pragma unroll
      for (int r = 0; r < 4; ++r) {
        const long gi = gi0 + r;
        out[gi * (long)NROWS + gj] = acc[m][n][r] + rw * (float)(gi - gj);
      }
    }
  }
}

// ---------------- slow-path GEMM1 (fp32 in-LDS split; proven fallback) ----------------
__device__ __forceinline__ void stage_split(const float* __restrict__ src, long ld,
                                            bf16_t (&hi)[128][LSTR],
                                            bf16_t (&lo)[128][LSTR],
                                            int t) {
#pragma unroll
  for (int i = 0; i < 4; ++i) {
    const int f = i * 256 + t;
    const int row = f >> 3;
    const int kq = (f & 7) << 2;
    const float4 v = *reinterpret_cast<const float4*>(src + (long)row * ld + kq);
    float vv[4] = {v.x, v.y, v.z, v.w};
    bf16x4_t h, l;
#pragma unroll
    for (int c = 0; c < 4; ++c) {
      bf16_t hh = (bf16_t)vv[c];
      h[c] = hh;
      l[c] = (bf16_t)(vv[c] - (float)hh);
    }
    *reinterpret_cast<bf16x4_t*>(&hi[row][kq]) = h;
    *reinterpret_cast<bf16x4_t*>(&lo[row][kq]) = l;
  }
}

__global__ __launch_bounds__(256) void k_gemm1_slow(
    const float* __restrict__ x, const float* __restrict__ W,
    const float* __restrict__ bias,
    bf16_t* __restrict__ xph, bf16_t* __restrict__ xpl) {
  __shared__ alignas(16) bf16_t Ahi[128][LSTR];
  __shared__ alignas(16) bf16_t Alo[128][LSTR];
  __shared__ alignas(16) bf16_t Bhi[128][LSTR];
  __shared__ alignas(16) bf16_t Blo[128][LSTR];

  const long brow = (long)blockIdx.y * 128;
  const long bcol = (long)blockIdx.x * 128;
  const int t = threadIdx.x, lane = t & 63;
  const int wr = ((t >> 6) >> 1) * 64, wc = ((t >> 6) & 1) * 64;
  const int fr = lane & 15, kg = lane >> 4;

  f32x4_t acc[4][4];
#pragma unroll
  for (int m = 0; m < 4; ++m)
#pragma unroll
    for (int n = 0; n < 4; ++n) acc[m][n] = f32x4_t{0.f, 0.f, 0.f, 0.f};

  const float* Abase = x + brow * DDIM;
  const float* Bbase = W + bcol * DDIM;
  for (int k0 = 0; k0 < DDIM; k0 += BK) {
    __syncthreads();
    stage_split(Abase + k0, DDIM, Ahi, Alo, t);
    stage_split(Bbase + k0, DDIM, Bhi, Blo, t);
    __syncthreads();

    bf16x8_t ah[4], al[4], bh[4], bl[4];
#pragma unroll
    for (int m = 0; m < 4; ++m) {
      ah[m] = *reinterpret_cast<const bf16x8_t*>(&Ahi[wr + m * 16 + fr][kg * 8]);
      al[m] = *reinterpret_cast<const bf16x8_t*>(&Alo[wr + m * 16 + fr][kg * 8]);
      bh[m] = *reinterpret_cast<const bf16x8_t*>(&Bhi[wc + m * 16 + fr][kg * 8]);
      bl[m] = *reinterpret_cast<const bf16x8_t*>(&Blo[wc + m * 16 + fr][kg * 8]);
    }
#pragma unroll
    for (int m = 0; m < 4; ++m)
#pragma unroll
      for (int n = 0; n < 4; ++n) {
        acc[m][n] = __builtin_amdgcn_mfma_f32_16x16x32_bf16(ah[m], bh[n], acc[m][n], 0, 0, 0);
        acc[m][n] = __builtin_amdgcn_mfma_f32_16x16x32_bf16(ah[m], bl[n], acc[m][n], 0, 0, 0);
        acc[m][n] = __builtin_amdgcn_mfma_f32_16x16x32_bf16(al[m], bh[n], acc[m][n], 0, 0, 0);
      }
  }

  const int cr = (lane >> 4) * 4, cc = lane & 15;
#pragma unroll
  for (int n = 0; n < 4; ++n) {
    const long col = bcol + wc + n * 16 + cc;
    const float bb = bias[col];
#pragma unroll
    for (int m = 0; m < 4; ++m) {
      const long row0 = brow + wr + m * 16 + cr;
#pragma unroll
      for (int r = 0; r < 4; ++r) {
        const float v = fmaxf(acc[m][n][r] + bb, 0.f);
        const bf16_t h = (bf16_t)v;
        xph[(row0 + r) * (long)DDIM + col] = h;
        xpl[(row0 + r) * (long)DDIM + col] = (bf16_t)(v - (float)h);
      }
    }
  }
}

// ---------------- row softmax over j<i; zeros elsewhere; row 0 all zeros ----------------
__global__ __launch_bounds__(256) void k_row_softmax(float* __restrict__ out, int n) {
  const int i = blockIdx.x;
  float* row = out + (size_t)i * n;
  const int L = i;
  const int t = threadIdx.x;
  __shared__ float red[4];

  float m = -3.402823466e+38f;
  for (int j = t; j < L; j += 256) m = fmaxf(m, row[j]);
#pragma unroll
  for (int o = 32; o > 0; o >>= 1) m = fmaxf(m, __shfl_down(m, o, 64));
  if ((t & 63) == 0) red[t >> 6] = m;
  __syncthreads();
  m = fmaxf(fmaxf(red[0], red[1]), fmaxf(red[2], red[3]));
  __syncthreads();

  float s = 0.f;
  for (int j = t; j < L; j += 256) s += expf(row[j] - m);
#pragma unroll
  for (int o = 32; o > 0; o >>= 1) s += __shfl_down(s, o, 64);
  if ((t & 63) == 0) red[t >> 6] = s;
  __syncthreads();
  s = red[0] + red[1] + red[2] + red[3];
  const float inv = (L > 0) ? 1.f / s : 0.f;

  for (int j = t; j < n; j += 256) {
    row[j] = (j < L) ? expf(row[j] - m) * inv : 0.f;
  }
}

extern "C" void kernel_launch(void* const* d_in, const int* in_sizes, int n_in,
                              void* d_out, int out_size, void* d_ws, size_t ws_size,
                              hipStream_t stream) {
  (void)in_sizes; (void)n_in; (void)out_size;
  const float* x = (const float*)d_in[0];
  const float* W = (const float*)d_in[1];
  const float* b = (const float*)d_in[2];
  const float* rw = (const float*)d_in[3];
  float* out = (float*)d_out;

  const size_t NX = (size_t)NROWS * DDIM;
  const size_t NW = (size_t)DDIM * DDIM;
  char* ws = (char*)d_ws;
  bf16_t* xph = (bf16_t*)ws;
  bf16_t* xpl = (bf16_t*)(ws + NX * 2);

  const int LDSB = 2 * 4 * 256 * BK * 2;  // 131072 B
  (void)hipFuncSetAttribute(reinterpret_cast<const void*>(k_gemm1_256),
                            hipFuncAttributeMaxDynamicSharedMemorySize, LDSB);
  (void)hipFuncSetAttribute(reinterpret_cast<const void*>(k_gemm2_256),
                            hipFuncAttributeMaxDynamicSharedMemorySize, LDSB);

  const size_t need_full = NX * 4 /*xph,xpl*/ + NX * 4 /*xh,xl*/ + NW * 4 /*Wh,Wl*/;
  if (ws_size >= need_full) {
    bf16_t* xh = (bf16_t*)(ws + NX * 4);
    bf16_t* xl = (bf16_t*)(ws + NX * 6);
    bf16_t* Wh = (bf16_t*)(ws + NX * 8);
    bf16_t* Wl = (bf16_t*)(ws + NX * 8 + NW * 2);
    k_split<<<(int)(NX / 1024), 256, 0, stream>>>(x, xh, xl);
    k_split<<<(int)(NW / 1024), 256, 0, stream>>>(W, Wh, Wl);
    k_gemm1_256<<<512, 512, LDSB, stream>>>(xh, xl, Wh, Wl, b, xph, xpl);
  } else {
    k_gemm1_slow<<<dim3(DDIM / 128, NROWS / 128), 256, 0, stream>>>(x, W, b, xph, xpl);
  }

  const int ntri = (NROWS / 256) * (NROWS / 256 + 1) / 2;  // 528
  k_gemm2_256<<<ntri, 512, LDSB, stream>>>(xph, xpl, rw, out);
  k_row_softmax<<<NROWS, 256, 0, stream>>>(out, NROWS);
}

// Round 4
// 1629.155 us; speedup vs baseline: 1.3678x; 1.0421x over previous
//
#include <hip/hip_runtime.h>
#include <hip/hip_bf16.h>
#include <stdint.h>

typedef __bf16 bf16_t;
typedef bf16_t bf16x8_t __attribute__((ext_vector_type(8)));
typedef bf16_t bf16x4_t __attribute__((ext_vector_type(4)));
typedef float f32x4_t __attribute__((ext_vector_type(4)));

#define NROWS 8192
#define DDIM  4096
#define BK 32
#define KTILES (DDIM / BK)  // 128
#define LSTR 40             // slow-path LDS stride

// ---------------- async 16B global->LDS ----------------
__device__ __forceinline__ void gload16(const void* g, void* s) {
  __builtin_amdgcn_global_load_lds(
      (const __attribute__((address_space(1))) void*)g,
      (__attribute__((address_space(3))) void*)s, 16, 0, 0);
}

// ---------------- presplit: fp32 -> (hi,lo) bf16 ----------------
__global__ __launch_bounds__(256) void k_split(const float* __restrict__ in,
                                               bf16_t* __restrict__ hi,
                                               bf16_t* __restrict__ lo) {
  const long i = ((long)blockIdx.x * 256 + threadIdx.x) * 4;
  const float4 v = *reinterpret_cast<const float4*>(in + i);
  float vv[4] = {v.x, v.y, v.z, v.w};
  bf16x4_t h, l;
#pragma unroll
  for (int c = 0; c < 4; ++c) {
    bf16_t hh = (bf16_t)vv[c];
    h[c] = hh;
    l[c] = (bf16_t)(vv[c] - (float)hh);
  }
  *reinterpret_cast<bf16x4_t*>(hi + i) = h;
  *reinterpret_cast<bf16x4_t*>(lo + i) = l;
}

// ---------------- 256x256 3-phase pipelined split-bf16 NT GEMM core ----------------
// planes: 0=Ah 1=Al 2=Bh 3=Bl. LDS: [2 buf][4 planes][256 rows][32 cols] bf16 = 128 KiB.
// T2 swizzle: physical 16B-granule p = logical_g ^ ((row>>1)&3). gload_lds dest stays
// linear (HW requirement); the inverse permutation is applied on the per-lane GLOBAL
// source granule, and the forward XOR on every ds_read column (rule #21: both sides).
typedef bf16_t lds_buf_t[4][256][BK];

__device__ __forceinline__ void gemm_core256(
    const bf16_t* __restrict__ pAh, const bf16_t* __restrict__ pAl, long lda,
    const bf16_t* __restrict__ pBh, const bf16_t* __restrict__ pBl, long ldb,
    lds_buf_t* sm, f32x4_t (&acc)[8][4]) {
  const int t = threadIdx.x, lane = t & 63, w = t >> 6;
  const int fr = lane & 15, kg = lane >> 4;
  const int wr = (w >> 2) * 128, wc = (w & 3) * 64;
  const int w32 = w * 32;
  const int sr0 = w32 + (lane >> 2);                      // staging row for this lane
  const int sg = (((lane & 3) ^ ((lane >> 3) & 3)) * 8);  // pre-swizzled global granule
  const int kge = (kg ^ ((fr >> 1) & 3)) * 8;             // swizzled ds_read col (elems)

#pragma unroll
  for (int m = 0; m < 8; ++m)
#pragma unroll
    for (int n = 0; n < 4; ++n) acc[m][n] = f32x4_t{0.f, 0.f, 0.f, 0.f};

  const bf16_t* gAh = pAh + (long)sr0 * lda + sg;
  const bf16_t* gAl = pAl + (long)sr0 * lda + sg;
  const bf16_t* gBh = pBh + (long)sr0 * ldb + sg;
  const bf16_t* gBl = pBl + (long)sr0 * ldb + sg;
  const long a16 = 16 * lda, b16 = 16 * ldb;

  // dest is wave-uniform base; HW adds lane*16 -> row w32+(lane>>2)[+16], granule lane&3
  auto issue = [&](int buf, int plane, const bf16_t* g, long ld16, int k0) {
    gload16(g + k0, &sm[buf][plane][w32][0]);
    gload16(g + ld16 + k0, &sm[buf][plane][w32 + 16][0]);
  };

  bf16x8_t ah[8], al[8], bh[4], bl[4];
  auto read8 = [&](bf16x8_t(&R)[8], int buf, int plane) {
#pragma unroll
    for (int m = 0; m < 8; ++m)
      R[m] = *reinterpret_cast<const bf16x8_t*>(&sm[buf][plane][wr + m * 16 + fr][kge]);
  };
  auto read4 = [&](bf16x8_t(&R)[4], int buf, int plane) {
#pragma unroll
    for (int n = 0; n < 4; ++n)
      R[n] = *reinterpret_cast<const bf16x8_t*>(&sm[buf][plane][wc + n * 16 + fr][kge]);
  };
  auto mfma32 = [&](bf16x8_t(&A)[8], bf16x8_t(&B)[4]) {
    __builtin_amdgcn_s_setprio(1);
#pragma unroll
    for (int m = 0; m < 8; ++m)
#pragma unroll
      for (int n = 0; n < 4; ++n)
        acc[m][n] = __builtin_amdgcn_mfma_f32_16x16x32_bf16(A[m], B[n], acc[m][n], 0, 0, 0);
    __builtin_amdgcn_s_setprio(0);
  };

  // prologue: tile 0, issue order Ah,Bh,Bl,Al (8 loads/thread)
  issue(0, 0, gAh, a16, 0);
  issue(0, 2, gBh, b16, 0);
  issue(0, 3, gBl, b16, 0);
  issue(0, 1, gAl, a16, 0);
  asm volatile("s_waitcnt vmcnt(4)" ::: "memory");  // Ah,Bh(0) landed
  __builtin_amdgcn_s_barrier();

  // steady state: per-thread outstanding entering phase0 = [Bl(kt),Al(kt)] (4)
  for (int kt = 0; kt < KTILES - 1; ++kt) {
    const int c = kt & 1;
    const int k0 = (kt + 1) * BK;
    // ---- phase 0: Ah*Bh ----
    read8(ah, c, 0);
    read4(bh, c, 2);
    issue(c ^ 1, 0, gAh, a16, k0);
    issue(c ^ 1, 2, gBh, b16, k0);
    __builtin_amdgcn_s_barrier();
    mfma32(ah, bh);
    asm volatile("s_waitcnt vmcnt(6)" ::: "memory");  // Bl(kt) landed
    __builtin_amdgcn_s_barrier();
    // ---- phase 1: Ah*Bl ----
    read4(bl, c, 3);
    issue(c ^ 1, 3, gBl, b16, k0);
    __builtin_amdgcn_s_barrier();
    mfma32(ah, bl);
    asm volatile("s_waitcnt vmcnt(6)" ::: "memory");  // Al(kt) landed
    __builtin_amdgcn_s_barrier();
    // ---- phase 2: Al*Bh ----
    read8(al, c, 1);
    issue(c ^ 1, 1, gAl, a16, k0);
    __builtin_amdgcn_s_barrier();
    mfma32(al, bh);
    asm volatile("s_waitcnt vmcnt(4)" ::: "memory");  // Ah,Bh(kt+1) landed
    __builtin_amdgcn_s_barrier();
  }
  // ---- peeled last tile: drain 2 -> 0 ----
  {
    const int c = (KTILES - 1) & 1;
    read8(ah, c, 0);
    read4(bh, c, 2);
    __builtin_amdgcn_s_barrier();
    mfma32(ah, bh);
    asm volatile("s_waitcnt vmcnt(2)" ::: "memory");  // Bl(last) landed
    __builtin_amdgcn_s_barrier();
    read4(bl, c, 3);
    __builtin_amdgcn_s_barrier();
    mfma32(ah, bl);
    asm volatile("s_waitcnt vmcnt(0)" ::: "memory");  // Al(last) landed
    __builtin_amdgcn_s_barrier();
    read8(al, c, 1);
    mfma32(al, bh);
  }
}

// ---------------- GEMM1 fast: xp(hi,lo) = split(relu(x @ W^T + b)) ----------------
__global__ __launch_bounds__(512, 2) void k_gemm1_256(
    const bf16_t* __restrict__ xh, const bf16_t* __restrict__ xl,
    const bf16_t* __restrict__ Wh, const bf16_t* __restrict__ Wl,
    const float* __restrict__ bias,
    bf16_t* __restrict__ xph, bf16_t* __restrict__ xpl) {
  extern __shared__ char smraw[];
  lds_buf_t* sm = (lds_buf_t*)smraw;

  int bid = (int)blockIdx.x;
  bid = (bid & 7) * 64 + (bid >> 3);  // 512 blocks, XCD-chunked (bijective)
  const int bx = bid & 15, by = bid >> 4;
  const long brow = (long)by * 256, bcol = (long)bx * 256;

  f32x4_t acc[8][4];
  gemm_core256(xh + brow * DDIM, xl + brow * DDIM, DDIM,
               Wh + bcol * DDIM, Wl + bcol * DDIM, DDIM, sm, acc);

  const int t = threadIdx.x, lane = t & 63, w = t >> 6;
  const int wr = (w >> 2) * 128, wc = (w & 3) * 64;
  const int cr = (lane >> 4) * 4, cc = lane & 15;
#pragma unroll
  for (int n = 0; n < 4; ++n) {
    const long col = bcol + wc + n * 16 + cc;
    const float bb = bias[col];
#pragma unroll
    for (int m = 0; m < 8; ++m) {
      const long row0 = brow + wr + m * 16 + cr;
#pragma unroll
      for (int r = 0; r < 4; ++r) {
        const float v = fmaxf(acc[m][n][r] + bb, 0.f);
        const bf16_t h = (bf16_t)v;
        xph[(row0 + r) * (long)DDIM + col] = h;
        xpl[(row0 + r) * (long)DDIM + col] = (bf16_t)(v - (float)h);
      }
    }
  }
}

// ---------------- GEMM2 fast: lower-tri 256x256 blocks ----------------
__global__ __launch_bounds__(512, 2) void k_gemm2_256(
    const bf16_t* __restrict__ xph, const bf16_t* __restrict__ xpl,
    const float* __restrict__ rwp, float* __restrict__ out) {
  extern __shared__ char smraw[];
  lds_buf_t* sm = (lds_buf_t*)smraw;

  int bid = (int)blockIdx.x;
  bid = (bid & 7) * 66 + (bid >> 3);  // 528 = 8*66, XCD-chunked (bijective)
  int by = (int)((sqrtf(8.f * (float)bid + 1.f) - 1.f) * 0.5f);
  while ((by + 1) * (by + 2) / 2 <= bid) ++by;
  while (by * (by + 1) / 2 > bid) --by;
  const int bx = bid - by * (by + 1) / 2;

  const long brow = (long)by * 256, bcol = (long)bx * 256;
  f32x4_t acc[8][4];
  gemm_core256(xph + brow * DDIM, xpl + brow * DDIM, DDIM,
               xph + bcol * DDIM, xpl + bcol * DDIM, DDIM, sm, acc);

  const float rw = rwp[0];
  const int t = threadIdx.x, lane = t & 63, w = t >> 6;
  const int wr = (w >> 2) * 128, wc = (w & 3) * 64;
  const int cr = (lane >> 4) * 4, cc = lane & 15;
#pragma unroll
  for (int n = 0; n < 4; ++n) {
    const long gj = bcol + wc + n * 16 + cc;
#pragma unroll
    for (int m = 0; m < 8; ++m) {
      const long gi0 = brow + wr + m * 16 + cr;
#pragma unroll
      for (int r = 0; r < 4; ++r) {
        const long gi = gi0 + r;
        out[gi * (long)NROWS + gj] = acc[m][n][r] + rw * (float)(gi - gj);
      }
    }
  }
}

// ---------------- slow-path GEMM1 (fp32 in-LDS split; proven fallback) ----------------
__device__ __forceinline__ void stage_split(const float* __restrict__ src, long ld,
                                            bf16_t (&hi)[128][LSTR],
                                            bf16_t (&lo)[128][LSTR],
                                            int t) {
#pragma unroll
  for (int i = 0; i < 4; ++i) {
    const int f = i * 256 + t;
    const int row = f >> 3;
    const int kq = (f & 7) << 2;
    const float4 v = *reinterpret_cast<const float4*>(src + (long)row * ld + kq);
    float vv[4] = {v.x, v.y, v.z, v.w};
    bf16x4_t h, l;
#pragma unroll
    for (int c = 0; c < 4; ++c) {
      bf16_t hh = (bf16_t)vv[c];
      h[c] = hh;
      l[c] = (bf16_t)(vv[c] - (float)hh);
    }
    *reinterpret_cast<bf16x4_t*>(&hi[row][kq]) = h;
    *reinterpret_cast<bf16x4_t*>(&lo[row][kq]) = l;
  }
}

__global__ __launch_bounds__(256) void k_gemm1_slow(
    const float* __restrict__ x, const float* __restrict__ W,
    const float* __restrict__ bias,
    bf16_t* __restrict__ xph, bf16_t* __restrict__ xpl) {
  __shared__ alignas(16) bf16_t Ahi[128][LSTR];
  __shared__ alignas(16) bf16_t Alo[128][LSTR];
  __shared__ alignas(16) bf16_t Bhi[128][LSTR];
  __shared__ alignas(16) bf16_t Blo[128][LSTR];

  const long brow = (long)blockIdx.y * 128;
  const long bcol = (long)blockIdx.x * 128;
  const int t = threadIdx.x, lane = t & 63;
  const int wr = ((t >> 6) >> 1) * 64, wc = ((t >> 6) & 1) * 64;
  const int fr = lane & 15, kg = lane >> 4;

  f32x4_t acc[4][4];
#pragma unroll
  for (int m = 0; m < 4; ++m)
#pragma unroll
    for (int n = 0; n < 4; ++n) acc[m][n] = f32x4_t{0.f, 0.f, 0.f, 0.f};

  const float* Abase = x + brow * DDIM;
  const float* Bbase = W + bcol * DDIM;
  for (int k0 = 0; k0 < DDIM; k0 += BK) {
    __syncthreads();
    stage_split(Abase + k0, DDIM, Ahi, Alo, t);
    stage_split(Bbase + k0, DDIM, Bhi, Blo, t);
    __syncthreads();

    bf16x8_t ah[4], al[4], bh[4], bl[4];
#pragma unroll
    for (int m = 0; m < 4; ++m) {
      ah[m] = *reinterpret_cast<const bf16x8_t*>(&Ahi[wr + m * 16 + fr][kg * 8]);
      al[m] = *reinterpret_cast<const bf16x8_t*>(&Alo[wr + m * 16 + fr][kg * 8]);
      bh[m] = *reinterpret_cast<const bf16x8_t*>(&Bhi[wc + m * 16 + fr][kg * 8]);
      bl[m] = *reinterpret_cast<const bf16x8_t*>(&Blo[wc + m * 16 + fr][kg * 8]);
    }
#pragma unroll
    for (int m = 0; m < 4; ++m)
#pragma unroll
      for (int n = 0; n < 4; ++n) {
        acc[m][n] = __builtin_amdgcn_mfma_f32_16x16x32_bf16(ah[m], bh[n], acc[m][n], 0, 0, 0);
        acc[m][n] = __builtin_amdgcn_mfma_f32_16x16x32_bf16(ah[m], bl[n], acc[m][n], 0, 0, 0);
        acc[m][n] = __builtin_amdgcn_mfma_f32_16x16x32_bf16(al[m], bh[n], acc[m][n], 0, 0, 0);
      }
  }

  const int cr = (lane >> 4) * 4, cc = lane & 15;
#pragma unroll
  for (int n = 0; n < 4; ++n) {
    const long col = bcol + wc + n * 16 + cc;
    const float bb = bias[col];
#pragma unroll
    for (int m = 0; m < 4; ++m) {
      const long row0 = brow + wr + m * 16 + cr;
#pragma unroll
      for (int r = 0; r < 4; ++r) {
        const float v = fmaxf(acc[m][n][r] + bb, 0.f);
        const bf16_t h = (bf16_t)v;
        xph[(row0 + r) * (long)DDIM + col] = h;
        xpl[(row0 + r) * (long)DDIM + col] = (bf16_t)(v - (float)h);
      }
    }
  }
}

// ---------------- row softmax over j<i; zeros elsewhere; row 0 all zeros ----------------
__global__ __launch_bounds__(256) void k_row_softmax(float* __restrict__ out, int n) {
  const int i = blockIdx.x;
  float* row = out + (size_t)i * n;
  const int L = i;
  const int t = threadIdx.x;
  __shared__ float red[4];

  float m = -3.402823466e+38f;
  for (int j = t; j < L; j += 256) m = fmaxf(m, row[j]);
#pragma unroll
  for (int o = 32; o > 0; o >>= 1) m = fmaxf(m, __shfl_down(m, o, 64));
  if ((t & 63) == 0) red[t >> 6] = m;
  __syncthreads();
  m = fmaxf(fmaxf(red[0], red[1]), fmaxf(red[2], red[3]));
  __syncthreads();

  float s = 0.f;
  for (int j = t; j < L; j += 256) s += expf(row[j] - m);
#pragma unroll
  for (int o = 32; o > 0; o >>= 1) s += __shfl_down(s, o, 64);
  if ((t & 63) == 0) red[t >> 6] = s;
  __syncthreads();
  s = red[0] + red[1] + red[2] + red[3];
  const float inv = (L > 0) ? 1.f / s : 0.f;

  for (int j = t; j < n; j += 256) {
    row[j] = (j < L) ? expf(row[j] - m) * inv : 0.f;
  }
}

extern "C" void kernel_launch(void* const* d_in, const int* in_sizes, int n_in,
                              void* d_out, int out_size, void* d_ws, size_t ws_size,
                              hipStream_t stream) {
  (void)in_sizes; (void)n_in; (void)out_size;
  const float* x = (const float*)d_in[0];
  const float* W = (const float*)d_in[1];
  const float* b = (const float*)d_in[2];
  const float* rw = (const float*)d_in[3];
  float* out = (float*)d_out;

  const size_t NX = (size_t)NROWS * DDIM;
  const size_t NW = (size_t)DDIM * DDIM;
  char* ws = (char*)d_ws;
  bf16_t* xph = (bf16_t*)ws;
  bf16_t* xpl = (bf16_t*)(ws + NX * 2);

  const int LDSB = 2 * 4 * 256 * BK * 2;  // 131072 B
  (void)hipFuncSetAttribute(reinterpret_cast<const void*>(k_gemm1_256),
                            hipFuncAttributeMaxDynamicSharedMemorySize, LDSB);
  (void)hipFuncSetAttribute(reinterpret_cast<const void*>(k_gemm2_256),
                            hipFuncAttributeMaxDynamicSharedMemorySize, LDSB);

  const size_t need_full = NX * 4 /*xph,xpl*/ + NX * 4 /*xh,xl*/ + NW * 4 /*Wh,Wl*/;
  if (ws_size >= need_full) {
    bf16_t* xh = (bf16_t*)(ws + NX * 4);
    bf16_t* xl = (bf16_t*)(ws + NX * 6);
    bf16_t* Wh = (bf16_t*)(ws + NX * 8);
    bf16_t* Wl = (bf16_t*)(ws + NX * 8 + NW * 2);
    k_split<<<(int)(NX / 1024), 256, 0, stream>>>(x, xh, xl);
    k_split<<<(int)(NW / 1024), 256, 0, stream>>>(W, Wh, Wl);
    k_gemm1_256<<<512, 512, LDSB, stream>>>(xh, xl, Wh, Wl, b, xph, xpl);
  } else {
    k_gemm1_slow<<<dim3(DDIM / 128, NROWS / 128), 256, 0, stream>>>(x, W, b, xph, xpl);
  }

  const int ntri = (NROWS / 256) * (NROWS / 256 + 1) / 2;  // 528
  k_gemm2_256<<<ntri, 512, LDSB, stream>>>(xph, xpl, rw, out);
  k_row_softmax<<<NROWS, 256, 0, stream>>>(out, NROWS);
}

// Round 5
// 1408.390 us; speedup vs baseline: 1.5821x; 1.1567x over previous
//
#include <hip/hip_runtime.h>
#include <hip/hip_bf16.h>
#include <stdint.h>

typedef _Float16 f16_t;
typedef f16_t f16x8_t __attribute__((ext_vector_type(8)));
typedef f16_t f16x4_t __attribute__((ext_vector_type(4)));
typedef float f32x4_t __attribute__((ext_vector_type(4)));

#define NROWS 8192
#define DDIM  4096
#define BK 32
#define KTILES (DDIM / BK)  // 128
#define LSTR 40             // slow-path LDS stride

// ---------------- async 16B global->LDS ----------------
__device__ __forceinline__ void gload16(const void* g, void* s) {
  __builtin_amdgcn_global_load_lds(
      (const __attribute__((address_space(1))) void*)g,
      (__attribute__((address_space(3))) void*)s, 16, 0, 0);
}

// ---------------- presplit: fp32 -> (hi,lo) f16 ----------------
__global__ __launch_bounds__(256) void k_split(const float* __restrict__ in,
                                               f16_t* __restrict__ hi,
                                               f16_t* __restrict__ lo) {
  const long i = ((long)blockIdx.x * 256 + threadIdx.x) * 4;
  const float4 v = *reinterpret_cast<const float4*>(in + i);
  float vv[4] = {v.x, v.y, v.z, v.w};
  f16x4_t h, l;
#pragma unroll
  for (int c = 0; c < 4; ++c) {
    f16_t hh = (f16_t)vv[c];
    h[c] = hh;
    l[c] = (f16_t)(vv[c] - (float)hh);
  }
  *reinterpret_cast<f16x4_t*>(hi + i) = h;
  *reinterpret_cast<f16x4_t*>(lo + i) = l;
}

// ======================= 3-phase core (GEMM1): full split-f16 =======================
// planes: 0=Ah 1=Al 2=Bh 3=Bl. LDS: [2][4][256][32] f16 = 128 KiB.
// T2 swizzle: physical 16B-granule p = g ^ ((row>>1)&3); inverse applied on per-lane
// global source granule (gload_lds dest must stay linear), forward XOR on ds_read col.
typedef f16_t lds4_t[4][256][BK];

__device__ __forceinline__ void gemm_core256_3p(
    const f16_t* __restrict__ pAh, const f16_t* __restrict__ pAl, long lda,
    const f16_t* __restrict__ pBh, const f16_t* __restrict__ pBl, long ldb,
    lds4_t* sm, f32x4_t (&acc)[8][4]) {
  const int t = threadIdx.x, lane = t & 63, w = t >> 6;
  const int fr = lane & 15, kg = lane >> 4;
  const int wr = (w >> 2) * 128, wc = (w & 3) * 64;
  const int w32 = w * 32;
  const int sr0 = w32 + (lane >> 2);
  const int sg = (((lane & 3) ^ ((lane >> 3) & 3)) * 8);
  const int kge = (kg ^ ((fr >> 1) & 3)) * 8;

#pragma unroll
  for (int m = 0; m < 8; ++m)
#pragma unroll
    for (int n = 0; n < 4; ++n) acc[m][n] = f32x4_t{0.f, 0.f, 0.f, 0.f};

  const f16_t* gAh = pAh + (long)sr0 * lda + sg;
  const f16_t* gAl = pAl + (long)sr0 * lda + sg;
  const f16_t* gBh = pBh + (long)sr0 * ldb + sg;
  const f16_t* gBl = pBl + (long)sr0 * ldb + sg;
  const long a16 = 16 * lda, b16 = 16 * ldb;

  auto issue = [&](int buf, int plane, const f16_t* g, long ld16, int k0) {
    gload16(g + k0, &sm[buf][plane][w32][0]);
    gload16(g + ld16 + k0, &sm[buf][plane][w32 + 16][0]);
  };

  f16x8_t ah[8], al[8], bh[4], bl[4];
  auto read8 = [&](f16x8_t(&R)[8], int buf, int plane) {
#pragma unroll
    for (int m = 0; m < 8; ++m)
      R[m] = *reinterpret_cast<const f16x8_t*>(&sm[buf][plane][wr + m * 16 + fr][kge]);
  };
  auto read4 = [&](f16x8_t(&R)[4], int buf, int plane) {
#pragma unroll
    for (int n = 0; n < 4; ++n)
      R[n] = *reinterpret_cast<const f16x8_t*>(&sm[buf][plane][wc + n * 16 + fr][kge]);
  };
  auto mfma32 = [&](f16x8_t(&A)[8], f16x8_t(&B)[4]) {
    __builtin_amdgcn_s_setprio(1);
#pragma unroll
    for (int m = 0; m < 8; ++m)
#pragma unroll
      for (int n = 0; n < 4; ++n)
        acc[m][n] = __builtin_amdgcn_mfma_f32_16x16x32_f16(A[m], B[n], acc[m][n], 0, 0, 0);
    __builtin_amdgcn_s_setprio(0);
  };

  issue(0, 0, gAh, a16, 0);
  issue(0, 2, gBh, b16, 0);
  issue(0, 3, gBl, b16, 0);
  issue(0, 1, gAl, a16, 0);
  asm volatile("s_waitcnt vmcnt(4)" ::: "memory");
  __builtin_amdgcn_s_barrier();

  for (int kt = 0; kt < KTILES - 1; ++kt) {
    const int c = kt & 1;
    const int k0 = (kt + 1) * BK;
    read8(ah, c, 0);
    read4(bh, c, 2);
    issue(c ^ 1, 0, gAh, a16, k0);
    issue(c ^ 1, 2, gBh, b16, k0);
    __builtin_amdgcn_s_barrier();
    mfma32(ah, bh);
    asm volatile("s_waitcnt vmcnt(6)" ::: "memory");
    __builtin_amdgcn_s_barrier();
    read4(bl, c, 3);
    issue(c ^ 1, 3, gBl, b16, k0);
    __builtin_amdgcn_s_barrier();
    mfma32(ah, bl);
    asm volatile("s_waitcnt vmcnt(6)" ::: "memory");
    __builtin_amdgcn_s_barrier();
    read8(al, c, 1);
    issue(c ^ 1, 1, gAl, a16, k0);
    __builtin_amdgcn_s_barrier();
    mfma32(al, bh);
    asm volatile("s_waitcnt vmcnt(4)" ::: "memory");
    __builtin_amdgcn_s_barrier();
  }
  {
    const int c = (KTILES - 1) & 1;
    read8(ah, c, 0);
    read4(bh, c, 2);
    __builtin_amdgcn_s_barrier();
    mfma32(ah, bh);
    asm volatile("s_waitcnt vmcnt(2)" ::: "memory");
    __builtin_amdgcn_s_barrier();
    read4(bl, c, 3);
    __builtin_amdgcn_s_barrier();
    mfma32(ah, bl);
    asm volatile("s_waitcnt vmcnt(0)" ::: "memory");
    __builtin_amdgcn_s_barrier();
    read8(al, c, 1);
    mfma32(al, bh);
  }
}

// ======================= 2-phase core (GEMM2): Ah * (Bh + Bl) =======================
// planes: 0=Ah 1=Bh 2=Bl. LDS: [2][3][256][32] f16 = 96 KiB.
// scores = xph . (xph + xpl)^T; dropped term xpl.xp ~ 2^-12 rel -> ~2e-3 logit sigma.
typedef f16_t lds3_t[3][256][BK];

__device__ __forceinline__ void gemm_core256_2p(
    const f16_t* __restrict__ pAh, long lda,
    const f16_t* __restrict__ pBh, const f16_t* __restrict__ pBl, long ldb,
    lds3_t* sm, f32x4_t (&acc)[8][4]) {
  const int t = threadIdx.x, lane = t & 63, w = t >> 6;
  const int fr = lane & 15, kg = lane >> 4;
  const int wr = (w >> 2) * 128, wc = (w & 3) * 64;
  const int w32 = w * 32;
  const int sr0 = w32 + (lane >> 2);
  const int sg = (((lane & 3) ^ ((lane >> 3) & 3)) * 8);
  const int kge = (kg ^ ((fr >> 1) & 3)) * 8;

#pragma unroll
  for (int m = 0; m < 8; ++m)
#pragma unroll
    for (int n = 0; n < 4; ++n) acc[m][n] = f32x4_t{0.f, 0.f, 0.f, 0.f};

  const f16_t* gAh = pAh + (long)sr0 * lda + sg;
  const f16_t* gBh = pBh + (long)sr0 * ldb + sg;
  const f16_t* gBl = pBl + (long)sr0 * ldb + sg;
  const long a16 = 16 * lda, b16 = 16 * ldb;

  auto issue = [&](int buf, int plane, const f16_t* g, long ld16, int k0) {
    gload16(g + k0, &sm[buf][plane][w32][0]);
    gload16(g + ld16 + k0, &sm[buf][plane][w32 + 16][0]);
  };

  f16x8_t ah[8], bh[4], bl[4];
  auto read8 = [&](f16x8_t(&R)[8], int buf, int plane) {
#pragma unroll
    for (int m = 0; m < 8; ++m)
      R[m] = *reinterpret_cast<const f16x8_t*>(&sm[buf][plane][wr + m * 16 + fr][kge]);
  };
  auto read4 = [&](f16x8_t(&R)[4], int buf, int plane) {
#pragma unroll
    for (int n = 0; n < 4; ++n)
      R[n] = *reinterpret_cast<const f16x8_t*>(&sm[buf][plane][wc + n * 16 + fr][kge]);
  };
  auto mfma32 = [&](f16x8_t(&A)[8], f16x8_t(&B)[4]) {
    __builtin_amdgcn_s_setprio(1);
#pragma unroll
    for (int m = 0; m < 8; ++m)
#pragma unroll
      for (int n = 0; n < 4; ++n)
        acc[m][n] = __builtin_amdgcn_mfma_f32_16x16x32_f16(A[m], B[n], acc[m][n], 0, 0, 0);
    __builtin_amdgcn_s_setprio(0);
  };

  // prologue: 6 loads/thread for tile 0
  issue(0, 0, gAh, a16, 0);
  issue(0, 1, gBh, b16, 0);
  issue(0, 2, gBl, b16, 0);
  asm volatile("s_waitcnt vmcnt(2)" ::: "memory");  // Ah,Bh(0) landed
  __builtin_amdgcn_s_barrier();

  // steady: entering phase0 of tile kt, outstanding = Bl(kt) [2]
  for (int kt = 0; kt < KTILES - 1; ++kt) {
    const int c = kt & 1;
    const int k0 = (kt + 1) * BK;
    // ---- phase 0: Ah*Bh ----
    read8(ah, c, 0);
    read4(bh, c, 1);
    issue(c ^ 1, 0, gAh, a16, k0);
    issue(c ^ 1, 1, gBh, b16, k0);  // outstanding: Bl(kt),Ah+1,Bh+1 = 6
    __builtin_amdgcn_s_barrier();
    mfma32(ah, bh);
    asm volatile("s_waitcnt vmcnt(4)" ::: "memory");  // Bl(kt) landed
    __builtin_amdgcn_s_barrier();
    // ---- phase 1: Ah*Bl ----
    read4(bl, c, 2);
    issue(c ^ 1, 2, gBl, b16, k0);  // outstanding: Ah+1,Bh+1,Bl+1 = 6
    __builtin_amdgcn_s_barrier();
    mfma32(ah, bl);
    asm volatile("s_waitcnt vmcnt(2)" ::: "memory");  // Ah,Bh(kt+1) landed
    __builtin_amdgcn_s_barrier();
  }
  // ---- peeled last tile ----
  {
    const int c = (KTILES - 1) & 1;
    read8(ah, c, 0);
    read4(bh, c, 1);
    __builtin_amdgcn_s_barrier();
    mfma32(ah, bh);
    asm volatile("s_waitcnt vmcnt(0)" ::: "memory");  // Bl(last) landed
    __builtin_amdgcn_s_barrier();
    read4(bl, c, 2);
    mfma32(ah, bl);
  }
}

// ---------------- GEMM1 fast: xp(hi,lo f16) = split(relu(x @ W^T + b)) ----------------
__global__ __launch_bounds__(512, 2) void k_gemm1_256(
    const f16_t* __restrict__ xh, const f16_t* __restrict__ xl,
    const f16_t* __restrict__ Wh, const f16_t* __restrict__ Wl,
    const float* __restrict__ bias,
    f16_t* __restrict__ xph, f16_t* __restrict__ xpl) {
  extern __shared__ char smraw[];
  lds4_t* sm = (lds4_t*)smraw;

  int bid = (int)blockIdx.x;
  bid = (bid & 7) * 64 + (bid >> 3);  // 512 blocks, XCD-chunked (bijective)
  const int bx = bid & 15, by = bid >> 4;
  const long brow = (long)by * 256, bcol = (long)bx * 256;

  f32x4_t acc[8][4];
  gemm_core256_3p(xh + brow * DDIM, xl + brow * DDIM, DDIM,
                  Wh + bcol * DDIM, Wl + bcol * DDIM, DDIM, sm, acc);

  const int t = threadIdx.x, lane = t & 63, w = t >> 6;
  const int wr = (w >> 2) * 128, wc = (w & 3) * 64;
  const int cr = (lane >> 4) * 4, cc = lane & 15;
#pragma unroll
  for (int n = 0; n < 4; ++n) {
    const long col = bcol + wc + n * 16 + cc;
    const float bb = bias[col];
#pragma unroll
    for (int m = 0; m < 8; ++m) {
      const long row0 = brow + wr + m * 16 + cr;
#pragma unroll
      for (int r = 0; r < 4; ++r) {
        const float v = fmaxf(acc[m][n][r] + bb, 0.f);
        const f16_t h = (f16_t)v;
        xph[(row0 + r) * (long)DDIM + col] = h;
        xpl[(row0 + r) * (long)DDIM + col] = (f16_t)(v - (float)h);
      }
    }
  }
}

// ---------------- GEMM2 fast: lower-tri 256x256 blocks, 2-phase ----------------
__global__ __launch_bounds__(512, 2) void k_gemm2_256(
    const f16_t* __restrict__ xph, const f16_t* __restrict__ xpl,
    const float* __restrict__ rwp, float* __restrict__ out) {
  extern __shared__ char smraw[];
  lds3_t* sm = (lds3_t*)smraw;

  int bid = (int)blockIdx.x;
  bid = (bid & 7) * 66 + (bid >> 3);  // 528 = 8*66, XCD-chunked (bijective)
  int by = (int)((sqrtf(8.f * (float)bid + 1.f) - 1.f) * 0.5f);
  while ((by + 1) * (by + 2) / 2 <= bid) ++by;
  while (by * (by + 1) / 2 > bid) --by;
  const int bx = bid - by * (by + 1) / 2;

  const long brow = (long)by * 256, bcol = (long)bx * 256;
  f32x4_t acc[8][4];
  gemm_core256_2p(xph + brow * DDIM, DDIM,
                  xph + bcol * DDIM, xpl + bcol * DDIM, DDIM, sm, acc);

  const float rw = rwp[0];
  const int t = threadIdx.x, lane = t & 63, w = t >> 6;
  const int wr = (w >> 2) * 128, wc = (w & 3) * 64;
  const int cr = (lane >> 4) * 4, cc = lane & 15;
#pragma unroll
  for (int n = 0; n < 4; ++n) {
    const long gj = bcol + wc + n * 16 + cc;
#pragma unroll
    for (int m = 0; m < 8; ++m) {
      const long gi0 = brow + wr + m * 16 + cr;
#pragma unroll
      for (int r = 0; r < 4; ++r) {
        const long gi = gi0 + r;
        out[gi * (long)NROWS + gj] = acc[m][n][r] + rw * (float)(gi - gj);
      }
    }
  }
}

// ---------------- slow-path GEMM1 (fp32 in-LDS split; fallback) ----------------
__device__ __forceinline__ void stage_split(const float* __restrict__ src, long ld,
                                            f16_t (&hi)[128][LSTR],
                                            f16_t (&lo)[128][LSTR],
                                            int t) {
#pragma unroll
  for (int i = 0; i < 4; ++i) {
    const int f = i * 256 + t;
    const int row = f >> 3;
    const int kq = (f & 7) << 2;
    const float4 v = *reinterpret_cast<const float4*>(src + (long)row * ld + kq);
    float vv[4] = {v.x, v.y, v.z, v.w};
    f16x4_t h, l;
#pragma unroll
    for (int c = 0; c < 4; ++c) {
      f16_t hh = (f16_t)vv[c];
      h[c] = hh;
      l[c] = (f16_t)(vv[c] - (float)hh);
    }
    *reinterpret_cast<f16x4_t*>(&hi[row][kq]) = h;
    *reinterpret_cast<f16x4_t*>(&lo[row][kq]) = l;
  }
}

__global__ __launch_bounds__(256) void k_gemm1_slow(
    const float* __restrict__ x, const float* __restrict__ W,
    const float* __restrict__ bias,
    f16_t* __restrict__ xph, f16_t* __restrict__ xpl) {
  __shared__ alignas(16) f16_t Ahi[128][LSTR];
  __shared__ alignas(16) f16_t Alo[128][LSTR];
  __shared__ alignas(16) f16_t Bhi[128][LSTR];
  __shared__ alignas(16) f16_t Blo[128][LSTR];

  const long brow = (long)blockIdx.y * 128;
  const long bcol = (long)blockIdx.x * 128;
  const int t = threadIdx.x, lane = t & 63;
  const int wr = ((t >> 6) >> 1) * 64, wc = ((t >> 6) & 1) * 64;
  const int fr = lane & 15, kg = lane >> 4;

  f32x4_t acc[4][4];
#pragma unroll
  for (int m = 0; m < 4; ++m)
#pragma unroll
    for (int n = 0; n < 4; ++n) acc[m][n] = f32x4_t{0.f, 0.f, 0.f, 0.f};

  const float* Abase = x + brow * DDIM;
  const float* Bbase = W + bcol * DDIM;
  for (int k0 = 0; k0 < DDIM; k0 += BK) {
    __syncthreads();
    stage_split(Abase + k0, DDIM, Ahi, Alo, t);
    stage_split(Bbase + k0, DDIM, Bhi, Blo, t);
    __syncthreads();

    f16x8_t ah[4], al[4], bh[4], bl[4];
#pragma unroll
    for (int m = 0; m < 4; ++m) {
      ah[m] = *reinterpret_cast<const f16x8_t*>(&Ahi[wr + m * 16 + fr][kg * 8]);
      al[m] = *reinterpret_cast<const f16x8_t*>(&Alo[wr + m * 16 + fr][kg * 8]);
      bh[m] = *reinterpret_cast<const f16x8_t*>(&Bhi[wc + m * 16 + fr][kg * 8]);
      bl[m] = *reinterpret_cast<const f16x8_t*>(&Blo[wc + m * 16 + fr][kg * 8]);
    }
#pragma unroll
    for (int m = 0; m < 4; ++m)
#pragma unroll
      for (int n = 0; n < 4; ++n) {
        acc[m][n] = __builtin_amdgcn_mfma_f32_16x16x32_f16(ah[m], bh[n], acc[m][n], 0, 0, 0);
        acc[m][n] = __builtin_amdgcn_mfma_f32_16x16x32_f16(ah[m], bl[n], acc[m][n], 0, 0, 0);
        acc[m][n] = __builtin_amdgcn_mfma_f32_16x16x32_f16(al[m], bh[n], acc[m][n], 0, 0, 0);
      }
  }

  const int cr = (lane >> 4) * 4, cc = lane & 15;
#pragma unroll
  for (int n = 0; n < 4; ++n) {
    const long col = bcol + wc + n * 16 + cc;
    const float bb = bias[col];
#pragma unroll
    for (int m = 0; m < 4; ++m) {
      const long row0 = brow + wr + m * 16 + cr;
#pragma unroll
      for (int r = 0; r < 4; ++r) {
        const float v = fmaxf(acc[m][n][r] + bb, 0.f);
        const f16_t h = (f16_t)v;
        xph[(row0 + r) * (long)DDIM + col] = h;
        xpl[(row0 + r) * (long)DDIM + col] = (f16_t)(v - (float)h);
      }
    }
  }
}

// ---------------- row softmax over j<i; zeros elsewhere; row 0 all zeros ----------------
__global__ __launch_bounds__(256) void k_row_softmax(float* __restrict__ out, int n) {
  const int i = blockIdx.x;
  float* row = out + (size_t)i * n;
  const int L = i;
  const int t = threadIdx.x;
  __shared__ float red[4];

  float m = -3.402823466e+38f;
  for (int j = t; j < L; j += 256) m = fmaxf(m, row[j]);
#pragma unroll
  for (int o = 32; o > 0; o >>= 1) m = fmaxf(m, __shfl_down(m, o, 64));
  if ((t & 63) == 0) red[t >> 6] = m;
  __syncthreads();
  m = fmaxf(fmaxf(red[0], red[1]), fmaxf(red[2], red[3]));
  __syncthreads();

  float s = 0.f;
  for (int j = t; j < L; j += 256) s += expf(row[j] - m);
#pragma unroll
  for (int o = 32; o > 0; o >>= 1) s += __shfl_down(s, o, 64);
  if ((t & 63) == 0) red[t >> 6] = s;
  __syncthreads();
  s = red[0] + red[1] + red[2] + red[3];
  const float inv = (L > 0) ? 1.f / s : 0.f;

  for (int j = t; j < n; j += 256) {
    row[j] = (j < L) ? expf(row[j] - m) * inv : 0.f;
  }
}

extern "C" void kernel_launch(void* const* d_in, const int* in_sizes, int n_in,
                              void* d_out, int out_size, void* d_ws, size_t ws_size,
                              hipStream_t stream) {
  (void)in_sizes; (void)n_in; (void)out_size;
  const float* x = (const float*)d_in[0];
  const float* W = (const float*)d_in[1];
  const float* b = (const float*)d_in[2];
  const float* rw = (const float*)d_in[3];
  float* out = (float*)d_out;

  const size_t NX = (size_t)NROWS * DDIM;
  const size_t NW = (size_t)DDIM * DDIM;
  char* ws = (char*)d_ws;
  f16_t* xph = (f16_t*)ws;
  f16_t* xpl = (f16_t*)(ws + NX * 2);

  const int LDSB1 = 2 * 4 * 256 * BK * 2;  // 131072 B
  const int LDSB2 = 2 * 3 * 256 * BK * 2;  // 98304 B
  (void)hipFuncSetAttribute(reinterpret_cast<const void*>(k_gemm1_256),
                            hipFuncAttributeMaxDynamicSharedMemorySize, LDSB1);
  (void)hipFuncSetAttribute(reinterpret_cast<const void*>(k_gemm2_256),
                            hipFuncAttributeMaxDynamicSharedMemorySize, LDSB2);

  const size_t need_full = NX * 4 /*xph,xpl*/ + NX * 4 /*xh,xl*/ + NW * 4 /*Wh,Wl*/;
  if (ws_size >= need_full) {
    f16_t* xh = (f16_t*)(ws + NX * 4);
    f16_t* xl = (f16_t*)(ws + NX * 6);
    f16_t* Wh = (f16_t*)(ws + NX * 8);
    f16_t* Wl = (f16_t*)(ws + NX * 8 + NW * 2);
    k_split<<<(int)(NX / 1024), 256, 0, stream>>>(x, xh, xl);
    k_split<<<(int)(NW / 1024), 256, 0, stream>>>(W, Wh, Wl);
    k_gemm1_256<<<512, 512, LDSB1, stream>>>(xh, xl, Wh, Wl, b, xph, xpl);
  } else {
    k_gemm1_slow<<<dim3(DDIM / 128, NROWS / 128), 256, 0, stream>>>(x, W, b, xph, xpl);
  }

  const int ntri = (NROWS / 256) * (NROWS / 256 + 1) / 2;  // 528
  k_gemm2_256<<<ntri, 512, LDSB2, stream>>>(xph, xpl, rw, out);
  k_row_softmax<<<NROWS, 256, 0, stream>>>(out, NROWS);
}